// Round 2
// 684.432 us; speedup vs baseline: 1.0384x; 1.0384x over previous
//
#include <hip/hip_runtime.h>

// ATTConv: T=3, N=T+1=4 (3 neighbors + self), D=128, B=100000.
// emd[t,n] = h_neigh[t,n] for n<3, emd[t,3] = h_center[t].
// scores[t,n,b] = leakyrelu( dot(emd[t,n,b],w_e[t]) + dot(h_center[t,b],w_h[t]) + att_b[t] )
// attn = softmax over n; out[t,b,:] = sum_n attn * emd[t,n,b,:]
//
// Layout: one 32-lane half-wave per (t,b) row; each lane holds a 4-float
// vector (4 d's) of each of the 4 emd vectors. Memory-bound: ~768 MB min.
//
// R2 = R1 with the compile fix: __builtin_nontemporal_* requires a native
// clang vector (ext_vector_type), not HIP's float4 class.
//  - 2-D grid (blockIdx.y = t): kills the per-thread 64-bit div/mod.
//  - exact grid (B % 8 == 0 -> 12500 x-blocks), cheap 32-bit guard only.
//  - nontemporal loads on the 4 streamed emd vectors + nontemporal store
//    on out (768 MB streams once, no reuse). Weights/bias stay cacheable.

#define TT 3
#define NN 4          // TT + 1
#define DD 128
#define NEG_SLOPE 0.01f
#define ROWS_PER_BLOCK 8   // 256 threads / 32 lanes

typedef float f4 __attribute__((ext_vector_type(4)));

__global__ __launch_bounds__(256) void attconv_kernel(
    const float* __restrict__ h_center,  // (T,B,D)
    const float* __restrict__ h_neigh,   // (T,T,B,D)
    const float* __restrict__ att_w,     // (T,2D)
    const float* __restrict__ att_b,     // (T,)
    float* __restrict__ out,             // (T,B,D)
    int B)
{
    const int t    = blockIdx.y;                                 // 0..TT-1
    const int b    = blockIdx.x * ROWS_PER_BLOCK + (threadIdx.x >> 5);
    const int lane = threadIdx.x & 31;                           // 0..31
    if (b >= B) return;                                          // no-op when B%8==0

    // per-head weights: w_h = att_w[t][0:128], w_e = att_w[t][128:256]
    const f4* wv = (const f4*)(att_w + (size_t)t * 2 * DD);
    const f4 wh = wv[lane];
    const f4 we = wv[32 + lane];
    const float bias = att_b[t];

    // load the 4 emd vectors (3 neighbors + center) — coalesced 16B,
    // nontemporal (streamed once, no reuse)
    const size_t crow = ((size_t)t * B + b) * DD;
    f4 e[NN];
    e[NN - 1] = __builtin_nontemporal_load((const f4*)(h_center + crow) + lane);
    #pragma unroll
    for (int n = 0; n < TT; ++n) {
        const f4* ng = (const f4*)(h_neigh + (((size_t)t * TT + n) * B + b) * DD);
        e[n] = __builtin_nontemporal_load(ng + lane);
    }

    // partial dot products: s[0..3] = emd_n . w_e ; s[4] = center . w_h
    float s[NN + 1];
    #pragma unroll
    for (int n = 0; n < NN; ++n)
        s[n] = e[n].x * we.x + e[n].y * we.y + e[n].z * we.z + e[n].w * we.w;
    {
        const f4 c = e[NN - 1];
        s[NN] = c.x * wh.x + c.y * wh.y + c.z * wh.z + c.w * wh.w;
    }

    // reduce over the 32 lanes of this half-wave (xor offsets < 32 never
    // cross the 32-lane half boundary within the 64-lane wave)
    #pragma unroll
    for (int off = 16; off > 0; off >>= 1) {
        #pragma unroll
        for (int k = 0; k < NN + 1; ++k)
            s[k] += __shfl_xor(s[k], off);
    }

    // scores + leaky relu + softmax over NN=4 (redundant per lane — cheap)
    float sc[NN];
    float m = -1e30f;
    #pragma unroll
    for (int n = 0; n < NN; ++n) {
        float x = s[n] + s[NN] + bias;
        x = (x >= 0.f) ? x : NEG_SLOPE * x;
        sc[n] = x;
        m = fmaxf(m, x);
    }
    float denom = 0.f;
    #pragma unroll
    for (int n = 0; n < NN; ++n) {
        sc[n] = __expf(sc[n] - m);
        denom += sc[n];
    }
    const float inv = __frcp_rn(denom);

    f4 o = (f4)(0.f);
    #pragma unroll
    for (int n = 0; n < NN; ++n) {
        const float a = sc[n] * inv;
        o.x += a * e[n].x;
        o.y += a * e[n].y;
        o.z += a * e[n].z;
        o.w += a * e[n].w;
    }

    __builtin_nontemporal_store(o, (f4*)(out + crow) + lane);
}

extern "C" void kernel_launch(void* const* d_in, const int* in_sizes, int n_in,
                              void* d_out, int out_size, void* d_ws, size_t ws_size,
                              hipStream_t stream) {
    const float* h_center = (const float*)d_in[0];  // (T,B,D)
    const float* h_neigh  = (const float*)d_in[1];  // (T,T,B,D)
    const float* att_w    = (const float*)d_in[2];  // (T,2D)
    const float* att_b    = (const float*)d_in[3];  // (T,)
    float* out = (float*)d_out;

    const int B = in_sizes[0] / (TT * DD);          // 100000
    const int xblocks = (B + ROWS_PER_BLOCK - 1) / ROWS_PER_BLOCK;  // 12500
    dim3 grid((unsigned)xblocks, TT, 1);

    attconv_kernel<<<grid, 256, 0, stream>>>(
        h_center, h_neigh, att_w, att_b, out, B);
}